// Round 8
// baseline (276.329 us; speedup 1.0000x reference)
//
#include <hip/hip_runtime.h>
#include <hip/hip_bf16.h>

typedef __bf16 bf16;
typedef __bf16 bf16x8 __attribute__((ext_vector_type(8)));
typedef float f32x4 __attribute__((ext_vector_type(4)));
typedef float f32x16 __attribute__((ext_vector_type(16)));

#define B_   4
#define T_   2048
#define DM_  1024
#define DH_  1024
#define MROWS 8192

// ---------------------------------------------------------------------------
// fp32 -> bf16, 32 elems/thread. y<3: activations (1024 blocks each).
// y==3: the three GEMM weights packed by x>>7 (128 blocks each; Wo is NOT
// converted — scale_wo reads fp32 Wo directly since R7).
// ---------------------------------------------------------------------------
struct CvtJob { const float* src; bf16* dst; };
struct CvtArgs { CvtJob job[6]; };

__global__ __launch_bounds__(256) void cvt_kernel(CvtArgs args) {
  int base;
  CvtJob jb;
  if (blockIdx.y < 3) {
    jb = args.job[blockIdx.y];
    base = blockIdx.x * 2048;
  } else {
    int wj = blockIdx.x >> 7;
    if (wj >= 3) return;
    jb = args.job[3 + wj];
    base = (blockIdx.x & 127) * 2048;
  }
  int t2 = threadIdx.x * 2;
  const float4* s = (const float4*)jb.src;
  float4 a[4][2];
#pragma unroll
  for (int u = 0; u < 4; ++u) {
    a[u][0] = s[base + u * 512 + t2];
    a[u][1] = s[base + u * 512 + t2 + 1];
  }
#pragma unroll
  for (int u = 0; u < 4; ++u) {
    bf16x8 o;
    o[0] = (bf16)a[u][0].x; o[1] = (bf16)a[u][0].y;
    o[2] = (bf16)a[u][0].z; o[3] = (bf16)a[u][0].w;
    o[4] = (bf16)a[u][1].x; o[5] = (bf16)a[u][1].y;
    o[6] = (bf16)a[u][1].z; o[7] = (bf16)a[u][1].w;
    *(bf16x8*)(jb.dst + ((size_t)base + u * 512 + t2) * 4) = o;
  }
}

// ---------------------------------------------------------------------------
// C[M,N] = A[M,K] * B[N,K]^T, all-bf16 — byte-identical to the proven R3
// kernel (R4-R6 lessons: KV-fusion variants all lose to this packed 3-job
// form — MT=1 halves MFMA-per-barrier; 512-block dispatches de-pack).
// MTx64-row x 128-col tile, BK=64, 4 waves 2x2, MFMA 32x32x16,
// global_load_lds w=16, swizzle mask (row&7)^((row>>3)&7) both sides ->
// 0 bank conflicts. Epilogue mode: 0 = fp32; 1 = bf16(sigmoid); 2 = bf16.
// XCD swizzle (gridDim.x==8, gridDim.y%8==0): blocks sharing tileM land on
// one XCD so A rows are fetched ~once per XCD.
// R8: gemm2 now uses MT=2 as well (MFMA per staged byte 2.0/KB vs MT=1's
// 1.33/KB at identical LDS-read-per-staged-byte; the R2 MT=1 choice was an
// unmeasured occupancy hunch).
// ---------------------------------------------------------------------------
struct GemmJob { const bf16* A; const bf16* Bw; float* Cf; bf16* Cb; int mode; };
struct GemmArgs { GemmJob job[4]; int N; int K; };

template <int MT>
__global__ __launch_bounds__(256) void gemm_bt(GemmArgs ga) {
  const GemmJob jb = ga.job[blockIdx.z];
  const int N = ga.N, K = ga.K;
  constexpr int TM = MT * 64;               // tile rows
  __shared__ __align__(16) bf16 As[TM * 64];
  __shared__ __align__(16) bf16 Bs[128 * 64];

  const int tid  = threadIdx.x;
  const int lane = tid & 63;
  const int wave = tid >> 6;
  const int wm   = (wave >> 1) * (MT * 32);
  const int wn   = (wave & 1) * 64;

  const int f   = blockIdx.y * 8 + blockIdx.x;
  const int xcd = f & 7;
  const int j   = f >> 3;
  const int bn  = j & 7;
  const int bm  = (j >> 3) * 8 + xcd;
  const int tileM = bm * TM;
  const int tileN = bn * 128;

  f32x16 acc[MT][2] = {};

  const int sr = lane >> 3;

  // Uniform 64-bit bases (SGPR pair), advanced by scalar adds per K-step.
  // Write-side pre-swizzle: source chunk sc = (lane&7) ^ sr ^ (grp&7), so
  // LDS position p of tile-row r holds chunk g = p ^ (r&7) ^ ((r>>3)&7).
  const char* pa = (const char*)(jb.A  + (size_t)tileM * K);
  const char* pb = (const char*)(jb.Bw + (size_t)tileN * K);
  unsigned int offA[MT * 2], offB[4];
#pragma unroll
  for (int l = 0; l < MT * 2; ++l) {
    int grp = wave * (MT * 2) + l;
    int sc  = (lane & 7) ^ sr ^ (grp & 7);
    offA[l] = (unsigned int)(((grp * 8 + sr) * K + sc * 8) * 2);
  }
#pragma unroll
  for (int l = 0; l < 4; ++l) {
    int grp = wave * 4 + l;
    int sc  = (lane & 7) ^ sr ^ (grp & 7);
    offB[l] = (unsigned int)(((grp * 8 + sr) * K + sc * 8) * 2);
  }

  const int half = lane >> 5;   // k-group within 16-slice
  const int rc   = lane & 31;   // row (A) / col (B) within 32-tile

  for (int k0 = 0; k0 < K; k0 += 64) {
#pragma unroll
    for (int l = 0; l < MT * 2; ++l)
      __builtin_amdgcn_global_load_lds(
          (const __attribute__((address_space(1))) void*)(pa + offA[l]),
          (__attribute__((address_space(3))) void*)&As[(wave * (MT * 2) + l) * 512],
          16, 0, 0);
#pragma unroll
    for (int l = 0; l < 4; ++l)
      __builtin_amdgcn_global_load_lds(
          (const __attribute__((address_space(1))) void*)(pb + offB[l]),
          (__attribute__((address_space(3))) void*)&Bs[(wave * 4 + l) * 512],
          16, 0, 0);
    pa += 128;  // 64 bf16 K-advance
    pb += 128;
    __syncthreads();

#pragma unroll
    for (int s = 0; s < 2; ++s) {        // two 32-k halves; ks = s*2 + kk
      bf16x8 af[MT][2], bfr[2][2];
#pragma unroll
      for (int mt = 0; mt < MT; ++mt)
#pragma unroll
        for (int kk = 0; kk < 2; ++kk) {
          int row = wm + mt * 32 + rc;
          int chunk = ((s * 2 + kk) * 2 + half) ^ (row & 7) ^ ((row >> 3) & 7);
          af[mt][kk] = *(const bf16x8*)&As[row * 64 + chunk * 8];
        }
#pragma unroll
      for (int nt = 0; nt < 2; ++nt)
#pragma unroll
        for (int kk = 0; kk < 2; ++kk) {
          int row = wn + nt * 32 + rc;
          int chunk = ((s * 2 + kk) * 2 + half) ^ (row & 7) ^ ((row >> 3) & 7);
          bfr[nt][kk] = *(const bf16x8*)&Bs[row * 64 + chunk * 8];
        }
#pragma unroll
      for (int kk = 0; kk < 2; ++kk)
#pragma unroll
        for (int mt = 0; mt < MT; ++mt)
#pragma unroll
          for (int nt = 0; nt < 2; ++nt)
            acc[mt][nt] = __builtin_amdgcn_mfma_f32_32x32x16_bf16(
                af[mt][kk], bfr[nt][kk], acc[mt][nt], 0, 0, 0);
    }
    __syncthreads();
  }

  // C/D: col = lane&31, row = (reg&3) + 8*(reg>>2) + 4*(lane>>5)
  const int cn    = rc;
  const int rbase = half * 4;
  if (jb.mode == 0) {
#pragma unroll
    for (int mt = 0; mt < MT; ++mt)
#pragma unroll
      for (int nt = 0; nt < 2; ++nt)
#pragma unroll
        for (int r = 0; r < 16; ++r) {
          int row = tileM + wm + mt * 32 + rbase + (r & 3) + 8 * (r >> 2);
          int col = tileN + wn + nt * 32 + cn;
          jb.Cf[(size_t)row * N + col] = acc[mt][nt][r];
        }
  } else if (jb.mode == 1) {
#pragma unroll
    for (int mt = 0; mt < MT; ++mt)
#pragma unroll
      for (int nt = 0; nt < 2; ++nt)
#pragma unroll
        for (int r = 0; r < 16; ++r) {
          int row = tileM + wm + mt * 32 + rbase + (r & 3) + 8 * (r >> 2);
          int col = tileN + wn + nt * 32 + cn;
          jb.Cb[(size_t)row * N + col] =
              (bf16)(1.f / (1.f + __expf(-acc[mt][nt][r])));
        }
  } else {
#pragma unroll
    for (int mt = 0; mt < MT; ++mt)
#pragma unroll
      for (int nt = 0; nt < 2; ++nt)
#pragma unroll
        for (int r = 0; r < 16; ++r) {
          int row = tileM + wm + mt * 32 + rbase + (r & 3) + 8 * (r >> 2);
          int col = tileN + wn + nt * 32 + cn;
          jb.Cb[(size_t)row * N + col] = (bf16)acc[mt][nt][r];
        }
  }
}

// ---------------------------------------------------------------------------
// Pass A: per-block partial reduction, atomic-free. R8: 512 blocks x 4
// j-rows (was 256 x 8 = 1 block/CU — its 67 MB read was MLP-starved, not
// BW-bound). Thread-half h covers j in [blk*4+h*2, +2), 8 d each.
// Halves merge via LDS [idx][dt] (conflict-free), half 0 stores partials:
// part[blk][0:4096]=num(b,d), part[blk][4096:8192]=den(b,d).
// ---------------------------------------------------------------------------
__global__ __launch_bounds__(256) void reduce_kv(
    const bf16* __restrict__ Kb, const bf16* __restrict__ Vb,
    float* __restrict__ part) {
  __shared__ float lds[64 * 128];
  const int t = threadIdx.x;
  const int half = t >> 7;
  const int dt = t & 127;
  const int d = dt * 8;
  const int j0 = blockIdx.x * 4 + half * 2;
  const size_t bs = (size_t)T_ * DH_;
  float n[4][8] = {}, e[4][8] = {};
#pragma unroll
  for (int jj = 0; jj < 2; ++jj) {
    size_t off = (size_t)(j0 + jj) * DH_ + d;
    bf16x8 kk[4], vv[4];
#pragma unroll
    for (int b = 0; b < 4; ++b) {
      kk[b] = *(const bf16x8*)(Kb + off + b * bs);
      vv[b] = *(const bf16x8*)(Vb + off + b * bs);
    }
#pragma unroll
    for (int c = 0; c < 8; ++c) {
      float k0 = (float)kk[0][c], k1 = (float)kk[1][c];
      float k2 = (float)kk[2][c], k3 = (float)kk[3][c];
      float m = fmaxf(fmaxf(k0, k1), fmaxf(k2, k3));
      float w0 = __expf(k0 - m), w1 = __expf(k1 - m);
      float w2 = __expf(k2 - m), w3 = __expf(k3 - m);
      e[0][c] += w0; e[1][c] += w1; e[2][c] += w2; e[3][c] += w3;
      n[0][c] += w0 * (float)vv[0][c];
      n[1][c] += w1 * (float)vv[1][c];
      n[2][c] += w2 * (float)vv[2][c];
      n[3][c] += w3 * (float)vv[3][c];
    }
  }
  if (half) {
#pragma unroll
    for (int b = 0; b < 4; ++b)
#pragma unroll
      for (int c = 0; c < 8; ++c) {
        lds[(b * 8 + c) * 128 + dt] = n[b][c];
        lds[(32 + b * 8 + c) * 128 + dt] = e[b][c];
      }
  }
  __syncthreads();
  if (!half) {
    float* po = part + (size_t)blockIdx.x * 8192;
#pragma unroll
    for (int b = 0; b < 4; ++b)
#pragma unroll
      for (int c = 0; c < 8; ++c) {
        po[b * 1024 + d + c] = n[b][c] + lds[(b * 8 + c) * 128 + dt];
        po[4096 + b * 1024 + d + c] = e[b][c] + lds[(32 + b * 8 + c) * 128 + dt];
      }
  }
}

// ---------------------------------------------------------------------------
// Pass B: numden[slot] = sum over 512 blocks of part[i][slot].
// 64 blocks x 256 threads; thread-half sums 256 partials (unroll-8 ILP),
// halves merge via LDS. Coalesced: consecutive threads = consecutive slots.
// ---------------------------------------------------------------------------
__global__ __launch_bounds__(256) void finish_kv(
    const float* __restrict__ part, float* __restrict__ numden) {
  __shared__ float lds[128];
  const int t = threadIdx.x;
  const int half = t >> 7;
  const int sl = t & 127;
  const int slot = blockIdx.x * 128 + sl;
  float s = 0.f;
  for (int i = half * 256; i < half * 256 + 256; i += 8) {
#pragma unroll
    for (int u = 0; u < 8; ++u)
      s += part[(size_t)(i + u) * 8192 + slot];
  }
  if (half) lds[sl] = s;
  __syncthreads();
  if (!half) numden[slot] = s + lds[sl];
}

// ---------------------------------------------------------------------------
// Wo_b[b][m][h] = Wo[m][h] * num[b,h]/den[b,h]  (ratio folded into weight;
// exact: out[b] = (sig(Q[b]) ⊙ r[b]) @ Wo^T = sig(Q[b]) @ (Wo ⊙ r[b])^T
// since num/den are i-independent). Reads the ORIGINAL fp32 Wo (no cvt,
// one less bf16 rounding). grid (512, 4): b = y.
// ---------------------------------------------------------------------------
__global__ __launch_bounds__(256) void scale_wo(
    const float* __restrict__ Wo, const float* __restrict__ numden,
    bf16* __restrict__ out4) {
  const int b = blockIdx.y;
  size_t i = ((size_t)blockIdx.x * 256 + threadIdx.x) * 8;
  int h = (int)(i & (DH_ - 1));
  float4 w0 = *(const float4*)(Wo + i);
  float4 w1 = *(const float4*)(Wo + i + 4);
  const float* nu = numden + b * DH_ + h;
  const float* de = numden + 4096 + b * DH_ + h;
  float4 n0 = *(const float4*)nu;
  float4 n1 = *(const float4*)(nu + 4);
  float4 d0 = *(const float4*)de;
  float4 d1 = *(const float4*)(de + 4);
  bf16x8 o;
  o[0] = (bf16)(w0.x * n0.x / d0.x);
  o[1] = (bf16)(w0.y * n0.y / d0.y);
  o[2] = (bf16)(w0.z * n0.z / d0.z);
  o[3] = (bf16)(w0.w * n0.w / d0.w);
  o[4] = (bf16)(w1.x * n1.x / d1.x);
  o[5] = (bf16)(w1.y * n1.y / d1.y);
  o[6] = (bf16)(w1.z * n1.z / d1.z);
  o[7] = (bf16)(w1.w * n1.w / d1.w);
  *(bf16x8*)(out4 + (size_t)b * ((size_t)DM_ * DH_) + i) = o;
}

// ---------------------------------------------------------------------------
extern "C" void kernel_launch(void* const* d_in, const int* in_sizes, int n_in,
                              void* d_out, int out_size, void* d_ws, size_t ws_size,
                              hipStream_t stream) {
  const float* q  = (const float*)d_in[0];
  const float* k  = (const float*)d_in[1];
  const float* v  = (const float*)d_in[2];
  const float* Wq = (const float*)d_in[3];
  const float* Wk = (const float*)d_in[4];
  const float* Wv = (const float*)d_in[5];
  const float* Wo = (const float*)d_in[6];
  // d_in[7] = W_bias mathematically unused (exp_pos_bias == all-ones).
  float* out = (float*)d_out;

  char* ws = (char*)d_ws;
  size_t off = 0;
  auto alloc = [&](size_t bytes) {
    char* p = ws + off;
    off += (bytes + 255) & ~(size_t)255;
    return p;
  };
  const size_t actN = (size_t)MROWS * DM_;   // 8388608
  const size_t wN   = (size_t)DH_ * DM_;     // 1048576

  bf16* qb  = (bf16*)alloc(actN * 2);
  bf16* kb  = (bf16*)alloc(actN * 2);
  bf16* vb  = (bf16*)alloc(actN * 2);
  bf16* Wqb = (bf16*)alloc(wN * 2);
  bf16* Wkb = (bf16*)alloc(wN * 2);
  bf16* Wvb = (bf16*)alloc(wN * 2);
  bf16* Kb  = (bf16*)alloc(actN * 2);
  bf16* Vb  = (bf16*)alloc(actN * 2);
  bf16* Yb  = (bf16*)alloc(actN * 2);
  // Aliasing (all stream-ordered: qb/kb/vb are dead after gemm1):
  //   part   (16.78 MB, 512 slabs) -> kb region (16.78 MB, exact fit)
  //   numden (32 KB)               -> vb region
  //   Wob4   (8 MB)                -> qb region
  float* part   = (float*)kb;
  float* numden = (float*)vb;
  bf16*  Wob4   = (bf16*)qb;

  // 1) fp32 -> bf16 (activations + Wq/Wk/Wv; Wo stays fp32)
  CvtArgs ca;
  ca.job[0] = {q,  qb};
  ca.job[1] = {k,  kb};
  ca.job[2] = {v,  vb};
  ca.job[3] = {Wq, Wqb};
  ca.job[4] = {Wk, Wkb};
  ca.job[5] = {Wv, Wvb};
  cvt_kernel<<<dim3(1024, 4), 256, 0, stream>>>(ca);

  // 2) merged K/V/Q projections (async bf16 staging; Q epilogue = sigmoid)
  GemmArgs g1;
  g1.N = DH_; g1.K = DM_;
  g1.job[0] = {kb, Wkb, nullptr, Kb, 2};
  g1.job[1] = {vb, Wvb, nullptr, Vb, 2};
  g1.job[2] = {qb, Wqb, nullptr, Yb, 1};
  g1.job[3] = {nullptr, nullptr, nullptr, nullptr, 0};
  gemm_bt<2><<<dim3(8, MROWS / 128, 3), 256, 0, stream>>>(g1);

  // 3) two-pass atomic-free reduction (512 blocks: 2/CU for MLP)
  reduce_kv<<<dim3(512), 256, 0, stream>>>(Kb, Vb, part);
  finish_kv<<<dim3(64), 256, 0, stream>>>(part, numden);

  // 4) fold ratio into per-batch Wo copies (reads fp32 Wo directly)
  scale_wo<<<dim3(512, 4), 256, 0, stream>>>(Wo, numden, Wob4);

  // 5) out[b] = sig(Q[b]) @ (Wo ⊙ r[b])^T — 4 per-batch jobs, fp32 out,
  //    MT=2 128-row tiles (512 blocks): 1.5x MFMA per staged byte vs MT=1.
  GemmArgs g2;
  g2.N = DM_; g2.K = DH_;
  for (int b = 0; b < 4; ++b) {
    g2.job[b] = {Yb + (size_t)b * ((size_t)T_ * DH_),
                 Wob4 + (size_t)b * wN,
                 out + (size_t)b * ((size_t)T_ * DM_),
                 nullptr, 0};
  }
  gemm_bt<2><<<dim3(8, 16, 4), 256, 0, stream>>>(g2);
}

// Round 9
// 266.350 us; speedup vs baseline: 1.0375x; 1.0375x over previous
//
#include <hip/hip_runtime.h>
#include <hip/hip_bf16.h>

typedef __bf16 bf16;
typedef __bf16 bf16x8 __attribute__((ext_vector_type(8)));
typedef float f32x4 __attribute__((ext_vector_type(4)));
typedef float f32x16 __attribute__((ext_vector_type(16)));

#define B_   4
#define T_   2048
#define DM_  1024
#define DH_  1024
#define MROWS 8192

// ---------------------------------------------------------------------------
// fp32 -> bf16, 32 elems/thread. y<3: activations (1024 blocks each).
// y==3: the three GEMM weights packed by x>>7 (128 blocks each; Wo is NOT
// converted — scale_wo reads fp32 Wo directly).
// ---------------------------------------------------------------------------
struct CvtJob { const float* src; bf16* dst; };
struct CvtArgs { CvtJob job[6]; };

__global__ __launch_bounds__(256) void cvt_kernel(CvtArgs args) {
  int base;
  CvtJob jb;
  if (blockIdx.y < 3) {
    jb = args.job[blockIdx.y];
    base = blockIdx.x * 2048;
  } else {
    int wj = blockIdx.x >> 7;
    if (wj >= 3) return;
    jb = args.job[3 + wj];
    base = (blockIdx.x & 127) * 2048;
  }
  int t2 = threadIdx.x * 2;
  const float4* s = (const float4*)jb.src;
  float4 a[4][2];
#pragma unroll
  for (int u = 0; u < 4; ++u) {
    a[u][0] = s[base + u * 512 + t2];
    a[u][1] = s[base + u * 512 + t2 + 1];
  }
#pragma unroll
  for (int u = 0; u < 4; ++u) {
    bf16x8 o;
    o[0] = (bf16)a[u][0].x; o[1] = (bf16)a[u][0].y;
    o[2] = (bf16)a[u][0].z; o[3] = (bf16)a[u][0].w;
    o[4] = (bf16)a[u][1].x; o[5] = (bf16)a[u][1].y;
    o[6] = (bf16)a[u][1].z; o[7] = (bf16)a[u][1].w;
    *(bf16x8*)(jb.dst + ((size_t)base + u * 512 + t2) * 4) = o;
  }
}

// ---------------------------------------------------------------------------
// C[M,N] = A[M,K] * B[N,K]^T, all-bf16 — the proven R3/R7 kernel.
// MTx64-row x 128-col tile, BK=64, 4 waves 2x2, MFMA 32x32x16,
// global_load_lds w=16, swizzle mask (row&7)^((row>>3)&7) both sides ->
// 0 bank conflicts. Epilogue mode: 0 = fp32; 1 = bf16(sigmoid); 2 = bf16.
// XCD swizzle (gridDim.x==8, gridDim.y%8==0): blocks sharing tileM land on
// one XCD so A rows are fetched ~once per XCD.
// Session laws (measured): (1) KV-fusion variants lose to this packed
// 3-job form (R4-R6); (2) for this 2-barrier structure, blocks/CU >= 4
// beats per-wave MFMA density — gemm2 must be MT=1 @ 1024 blocks, NOT
// MT=2 @ 512 (R8: +7.8 us); (3) reduce_kv is BW-bound, 256 blocks is
// right (R8: 512 blocks regressed via doubled partial traffic).
// ---------------------------------------------------------------------------
struct GemmJob { const bf16* A; const bf16* Bw; float* Cf; bf16* Cb; int mode; };
struct GemmArgs { GemmJob job[4]; int N; int K; };

template <int MT>
__global__ __launch_bounds__(256) void gemm_bt(GemmArgs ga) {
  const GemmJob jb = ga.job[blockIdx.z];
  const int N = ga.N, K = ga.K;
  constexpr int TM = MT * 64;               // tile rows
  __shared__ __align__(16) bf16 As[TM * 64];
  __shared__ __align__(16) bf16 Bs[128 * 64];

  const int tid  = threadIdx.x;
  const int lane = tid & 63;
  const int wave = tid >> 6;
  const int wm   = (wave >> 1) * (MT * 32);
  const int wn   = (wave & 1) * 64;

  const int f   = blockIdx.y * 8 + blockIdx.x;
  const int xcd = f & 7;
  const int j   = f >> 3;
  const int bn  = j & 7;
  const int bm  = (j >> 3) * 8 + xcd;
  const int tileM = bm * TM;
  const int tileN = bn * 128;

  f32x16 acc[MT][2] = {};

  const int sr = lane >> 3;

  // Uniform 64-bit bases (SGPR pair), advanced by scalar adds per K-step.
  // Write-side pre-swizzle: source chunk sc = (lane&7) ^ sr ^ (grp&7), so
  // LDS position p of tile-row r holds chunk g = p ^ (r&7) ^ ((r>>3)&7).
  const char* pa = (const char*)(jb.A  + (size_t)tileM * K);
  const char* pb = (const char*)(jb.Bw + (size_t)tileN * K);
  unsigned int offA[MT * 2], offB[4];
#pragma unroll
  for (int l = 0; l < MT * 2; ++l) {
    int grp = wave * (MT * 2) + l;
    int sc  = (lane & 7) ^ sr ^ (grp & 7);
    offA[l] = (unsigned int)(((grp * 8 + sr) * K + sc * 8) * 2);
  }
#pragma unroll
  for (int l = 0; l < 4; ++l) {
    int grp = wave * 4 + l;
    int sc  = (lane & 7) ^ sr ^ (grp & 7);
    offB[l] = (unsigned int)(((grp * 8 + sr) * K + sc * 8) * 2);
  }

  const int half = lane >> 5;   // k-group within 16-slice
  const int rc   = lane & 31;   // row (A) / col (B) within 32-tile

  for (int k0 = 0; k0 < K; k0 += 64) {
#pragma unroll
    for (int l = 0; l < MT * 2; ++l)
      __builtin_amdgcn_global_load_lds(
          (const __attribute__((address_space(1))) void*)(pa + offA[l]),
          (__attribute__((address_space(3))) void*)&As[(wave * (MT * 2) + l) * 512],
          16, 0, 0);
#pragma unroll
    for (int l = 0; l < 4; ++l)
      __builtin_amdgcn_global_load_lds(
          (const __attribute__((address_space(1))) void*)(pb + offB[l]),
          (__attribute__((address_space(3))) void*)&Bs[(wave * 4 + l) * 512],
          16, 0, 0);
    pa += 128;  // 64 bf16 K-advance
    pb += 128;
    __syncthreads();

#pragma unroll
    for (int s = 0; s < 2; ++s) {        // two 32-k halves; ks = s*2 + kk
      bf16x8 af[MT][2], bfr[2][2];
#pragma unroll
      for (int mt = 0; mt < MT; ++mt)
#pragma unroll
        for (int kk = 0; kk < 2; ++kk) {
          int row = wm + mt * 32 + rc;
          int chunk = ((s * 2 + kk) * 2 + half) ^ (row & 7) ^ ((row >> 3) & 7);
          af[mt][kk] = *(const bf16x8*)&As[row * 64 + chunk * 8];
        }
#pragma unroll
      for (int nt = 0; nt < 2; ++nt)
#pragma unroll
        for (int kk = 0; kk < 2; ++kk) {
          int row = wn + nt * 32 + rc;
          int chunk = ((s * 2 + kk) * 2 + half) ^ (row & 7) ^ ((row >> 3) & 7);
          bfr[nt][kk] = *(const bf16x8*)&Bs[row * 64 + chunk * 8];
        }
#pragma unroll
      for (int kk = 0; kk < 2; ++kk)
#pragma unroll
        for (int mt = 0; mt < MT; ++mt)
#pragma unroll
          for (int nt = 0; nt < 2; ++nt)
            acc[mt][nt] = __builtin_amdgcn_mfma_f32_32x32x16_bf16(
                af[mt][kk], bfr[nt][kk], acc[mt][nt], 0, 0, 0);
    }
    __syncthreads();
  }

  // C/D: col = lane&31, row = (reg&3) + 8*(reg>>2) + 4*(lane>>5)
  const int cn    = rc;
  const int rbase = half * 4;
  if (jb.mode == 0) {
#pragma unroll
    for (int mt = 0; mt < MT; ++mt)
#pragma unroll
      for (int nt = 0; nt < 2; ++nt)
#pragma unroll
        for (int r = 0; r < 16; ++r) {
          int row = tileM + wm + mt * 32 + rbase + (r & 3) + 8 * (r >> 2);
          int col = tileN + wn + nt * 32 + cn;
          jb.Cf[(size_t)row * N + col] = acc[mt][nt][r];
        }
  } else if (jb.mode == 1) {
#pragma unroll
    for (int mt = 0; mt < MT; ++mt)
#pragma unroll
      for (int nt = 0; nt < 2; ++nt)
#pragma unroll
        for (int r = 0; r < 16; ++r) {
          int row = tileM + wm + mt * 32 + rbase + (r & 3) + 8 * (r >> 2);
          int col = tileN + wn + nt * 32 + cn;
          jb.Cb[(size_t)row * N + col] =
              (bf16)(1.f / (1.f + __expf(-acc[mt][nt][r])));
        }
  } else {
#pragma unroll
    for (int mt = 0; mt < MT; ++mt)
#pragma unroll
      for (int nt = 0; nt < 2; ++nt)
#pragma unroll
        for (int r = 0; r < 16; ++r) {
          int row = tileM + wm + mt * 32 + rbase + (r & 3) + 8 * (r >> 2);
          int col = tileN + wn + nt * 32 + cn;
          jb.Cb[(size_t)row * N + col] = (bf16)acc[mt][nt][r];
        }
  }
}

// ---------------------------------------------------------------------------
// Pass A: per-block partial reduction over 8 j-rows, atomic-free.
// m[j,d]=max_b K; w=exp(K-m); partial num/den summed over the block's j's.
// 256 blocks (1/CU; 512 regressed — R8). Thread-half h covers j in
// [blk*8+h*4, +4), 8 d each. Halves merge via LDS [idx][dt]
// (conflict-free), half 0 stores partials:
// part[blk][0:4096]=num(b,d), part[blk][4096:8192]=den(b,d).
// ---------------------------------------------------------------------------
__global__ __launch_bounds__(256) void reduce_kv(
    const bf16* __restrict__ Kb, const bf16* __restrict__ Vb,
    float* __restrict__ part) {
  __shared__ float lds[64 * 128];
  const int t = threadIdx.x;
  const int half = t >> 7;
  const int dt = t & 127;
  const int d = dt * 8;
  const int j0 = blockIdx.x * 8 + half * 4;
  const size_t bs = (size_t)T_ * DH_;
  float n[4][8] = {}, e[4][8] = {};
#pragma unroll
  for (int jj = 0; jj < 4; ++jj) {
    size_t off = (size_t)(j0 + jj) * DH_ + d;
    bf16x8 kk[4], vv[4];
#pragma unroll
    for (int b = 0; b < 4; ++b) {
      kk[b] = *(const bf16x8*)(Kb + off + b * bs);
      vv[b] = *(const bf16x8*)(Vb + off + b * bs);
    }
#pragma unroll
    for (int c = 0; c < 8; ++c) {
      float k0 = (float)kk[0][c], k1 = (float)kk[1][c];
      float k2 = (float)kk[2][c], k3 = (float)kk[3][c];
      float m = fmaxf(fmaxf(k0, k1), fmaxf(k2, k3));
      float w0 = __expf(k0 - m), w1 = __expf(k1 - m);
      float w2 = __expf(k2 - m), w3 = __expf(k3 - m);
      e[0][c] += w0; e[1][c] += w1; e[2][c] += w2; e[3][c] += w3;
      n[0][c] += w0 * (float)vv[0][c];
      n[1][c] += w1 * (float)vv[1][c];
      n[2][c] += w2 * (float)vv[2][c];
      n[3][c] += w3 * (float)vv[3][c];
    }
  }
  if (half) {
#pragma unroll
    for (int b = 0; b < 4; ++b)
#pragma unroll
      for (int c = 0; c < 8; ++c) {
        lds[(b * 8 + c) * 128 + dt] = n[b][c];
        lds[(32 + b * 8 + c) * 128 + dt] = e[b][c];
      }
  }
  __syncthreads();
  if (!half) {
    float* po = part + (size_t)blockIdx.x * 8192;
#pragma unroll
    for (int b = 0; b < 4; ++b)
#pragma unroll
      for (int c = 0; c < 8; ++c) {
        po[b * 1024 + d + c] = n[b][c] + lds[(b * 8 + c) * 128 + dt];
        po[4096 + b * 1024 + d + c] = e[b][c] + lds[(32 + b * 8 + c) * 128 + dt];
      }
  }
}

// ---------------------------------------------------------------------------
// Pass B: numden[slot] = sum over 256 blocks of part[i][slot].
// 64 blocks x 256 threads; thread-half sums 128 partials (unroll-8 ILP),
// halves merge via LDS. Coalesced: consecutive threads = consecutive slots.
// ---------------------------------------------------------------------------
__global__ __launch_bounds__(256) void finish_kv(
    const float* __restrict__ part, float* __restrict__ numden) {
  __shared__ float lds[128];
  const int t = threadIdx.x;
  const int half = t >> 7;
  const int sl = t & 127;
  const int slot = blockIdx.x * 128 + sl;
  float s = 0.f;
  for (int i = half * 128; i < half * 128 + 128; i += 8) {
#pragma unroll
    for (int u = 0; u < 8; ++u)
      s += part[(size_t)(i + u) * 8192 + slot];
  }
  if (half) lds[sl] = s;
  __syncthreads();
  if (!half) numden[slot] = s + lds[sl];
}

// ---------------------------------------------------------------------------
// Wo_b[b][m][h] = Wo[m][h] * num[b,h]/den[b,h]  (ratio folded into weight;
// exact: out[b] = (sig(Q[b]) ⊙ r[b]) @ Wo^T = sig(Q[b]) @ (Wo ⊙ r[b])^T
// since num/den are i-independent). Reads the ORIGINAL fp32 Wo (no cvt,
// one less bf16 rounding). grid (512, 4): b = y.
// ---------------------------------------------------------------------------
__global__ __launch_bounds__(256) void scale_wo(
    const float* __restrict__ Wo, const float* __restrict__ numden,
    bf16* __restrict__ out4) {
  const int b = blockIdx.y;
  size_t i = ((size_t)blockIdx.x * 256 + threadIdx.x) * 8;
  int h = (int)(i & (DH_ - 1));
  float4 w0 = *(const float4*)(Wo + i);
  float4 w1 = *(const float4*)(Wo + i + 4);
  const float* nu = numden + b * DH_ + h;
  const float* de = numden + 4096 + b * DH_ + h;
  float4 n0 = *(const float4*)nu;
  float4 n1 = *(const float4*)(nu + 4);
  float4 d0 = *(const float4*)de;
  float4 d1 = *(const float4*)(de + 4);
  bf16x8 o;
  o[0] = (bf16)(w0.x * n0.x / d0.x);
  o[1] = (bf16)(w0.y * n0.y / d0.y);
  o[2] = (bf16)(w0.z * n0.z / d0.z);
  o[3] = (bf16)(w0.w * n0.w / d0.w);
  o[4] = (bf16)(w1.x * n1.x / d1.x);
  o[5] = (bf16)(w1.y * n1.y / d1.y);
  o[6] = (bf16)(w1.z * n1.z / d1.z);
  o[7] = (bf16)(w1.w * n1.w / d1.w);
  *(bf16x8*)(out4 + (size_t)b * ((size_t)DM_ * DH_) + i) = o;
}

// ---------------------------------------------------------------------------
extern "C" void kernel_launch(void* const* d_in, const int* in_sizes, int n_in,
                              void* d_out, int out_size, void* d_ws, size_t ws_size,
                              hipStream_t stream) {
  const float* q  = (const float*)d_in[0];
  const float* k  = (const float*)d_in[1];
  const float* v  = (const float*)d_in[2];
  const float* Wq = (const float*)d_in[3];
  const float* Wk = (const float*)d_in[4];
  const float* Wv = (const float*)d_in[5];
  const float* Wo = (const float*)d_in[6];
  // d_in[7] = W_bias mathematically unused (exp_pos_bias == all-ones).
  float* out = (float*)d_out;

  char* ws = (char*)d_ws;
  size_t off = 0;
  auto alloc = [&](size_t bytes) {
    char* p = ws + off;
    off += (bytes + 255) & ~(size_t)255;
    return p;
  };
  const size_t actN = (size_t)MROWS * DM_;   // 8388608
  const size_t wN   = (size_t)DH_ * DM_;     // 1048576

  bf16* qb  = (bf16*)alloc(actN * 2);
  bf16* kb  = (bf16*)alloc(actN * 2);
  bf16* vb  = (bf16*)alloc(actN * 2);
  bf16* Wqb = (bf16*)alloc(wN * 2);
  bf16* Wkb = (bf16*)alloc(wN * 2);
  bf16* Wvb = (bf16*)alloc(wN * 2);
  bf16* Kb  = (bf16*)alloc(actN * 2);
  bf16* Vb  = (bf16*)alloc(actN * 2);
  bf16* Yb  = (bf16*)alloc(actN * 2);
  // Aliasing (all stream-ordered: qb/kb/vb are dead after gemm1):
  //   part   (8 MB)  -> kb region   (written by reduce_kv, after gemm1)
  //   numden (32 KB) -> vb region   (written by finish_kv)
  //   Wob4   (8 MB)  -> qb region   (written by scale_wo)
  float* part   = (float*)kb;
  float* numden = (float*)vb;
  bf16*  Wob4   = (bf16*)qb;

  // 1) fp32 -> bf16 (activations + Wq/Wk/Wv; Wo stays fp32)
  CvtArgs ca;
  ca.job[0] = {q,  qb};
  ca.job[1] = {k,  kb};
  ca.job[2] = {v,  vb};
  ca.job[3] = {Wq, Wqb};
  ca.job[4] = {Wk, Wkb};
  ca.job[5] = {Wv, Wvb};
  cvt_kernel<<<dim3(1024, 4), 256, 0, stream>>>(ca);

  // 2) merged K/V/Q projections (async bf16 staging; Q epilogue = sigmoid)
  GemmArgs g1;
  g1.N = DH_; g1.K = DM_;
  g1.job[0] = {kb, Wkb, nullptr, Kb, 2};
  g1.job[1] = {vb, Wvb, nullptr, Vb, 2};
  g1.job[2] = {qb, Wqb, nullptr, Yb, 1};
  g1.job[3] = {nullptr, nullptr, nullptr, nullptr, 0};
  gemm_bt<2><<<dim3(8, MROWS / 128, 3), 256, 0, stream>>>(g1);

  // 3) two-pass atomic-free reduction
  reduce_kv<<<dim3(256), 256, 0, stream>>>(Kb, Vb, part);
  finish_kv<<<dim3(64), 256, 0, stream>>>(part, numden);

  // 4) fold ratio into per-batch Wo copies (reads fp32 Wo directly)
  scale_wo<<<dim3(512, 4), 256, 0, stream>>>(Wo, numden, Wob4);

  // 5) out[b] = sig(Q[b]) @ (Wo ⊙ r[b])^T  — 4 per-batch jobs, fp32 out,
  //    64-row tiles (MT=1): 1024 blocks = 4/CU for latency hiding.
  GemmArgs g2;
  g2.N = DM_; g2.K = DH_;
  for (int b = 0; b < 4; ++b) {
    g2.job[b] = {Yb + (size_t)b * ((size_t)T_ * DH_),
                 Wob4 + (size_t)b * wN,
                 out + (size_t)b * ((size_t)T_ * DM_),
                 nullptr, 0};
  }
  gemm_bt<1><<<dim3(8, 32, 4), 256, 0, stream>>>(g2);
}